// Round 12
// baseline (343.986 us; speedup 1.0000x reference)
//
#include <hip/hip_runtime.h>
#include <hip/hip_bf16.h>

// Problem constants (GraphGRUCell_62019327754706)
// DTYPES (settled r4/r5): all float tensors FP32 in and out. int32 edges.
// r6: never clamp launch_bounds waves -> spills.
// r8: 4 nodes/wave @ block=256 => VGPR 64, no spill.
// r9: 8 nodes/wave => spills -> never.
// r11: half-wave node pairing REGRESSED. XCD swizzle WORKED -> keep.
// r12: dense union-range tiling + no-max softmax -> KEEP.
// r13: single-pass padded u16 bins -> fused 190, total 333 = BASE.
// r14/r15: fp16+fdot2 container-failed TWICE -> fdot2 BLACKLISTED.
// r16/r17: quarter-wave phase B CLOSED.
// r18-r21: environment theory REFUTED (r21 byte-exact r13 reproduces 189us).
//      unroll4 (r19, 234us) and pk_fma (r20, 228us) are GENUINELY harmful:
//      dense f-loops are schedule-fragile; compiler's rolled schedule wins.
//      NEVER touch dense-loop scheduling. fused = 112us VALU-busy + 77 stall.
// r22 (this): phase-A serial-chain cuts only (dataflow, not scheduling):
//      (1) mb[s] gather issued PARALLEL to k-gathers (was control-dependent
//          serial step); p = m ? exp(sc) : 0 at the end. Numerics identical.
//      (2) depth-1 prefetch of next tile's bins index (named regs, no
//          dynamic-index arrays) -- L2 latency hides under current tile.
#define BB 4
#define NN 20000
#define UU 64
#define EE 640000
#define FF 65              // U + D
#define SCALE_F 0.125f     // 1/sqrt(64)
#define PREP_BLOCKS 2500   // (B*N)/32
#define SCAT_BLOCKS 2500   // EE/256

typedef unsigned short u16;
typedef unsigned long long u64;

static inline size_t align_up(size_t x) { return (x + 255) & ~(size_t)255; }

__device__ __forceinline__ float u2f(unsigned int u) { return __uint_as_float(u); }
__device__ __forceinline__ u16 f2bf(float f) {
    __hip_bfloat16 h = __float2bfloat16(f);
    return *reinterpret_cast<u16*>(&h);
}

// ---------------- fat kernel: prep (even blocks) || bin-scatter (odd blocks)
// prep: k,v (bf16) + mask, 8 nodes/wave. scatter: bins[dst*cap+pos]=src.
__global__ __launch_bounds__(256) void prep_scatter_kernel(
    const float* __restrict__ state, const float* __restrict__ inputs,
    const float* __restrict__ Wk, const float* __restrict__ bk,
    const float* __restrict__ Wv, const float* __restrict__ bv,
    u16* __restrict__ kbuf, u16* __restrict__ vbuf,
    unsigned char* __restrict__ maskb,
    const int* __restrict__ edst, const int* __restrict__ esrc,
    int* __restrict__ counts, u16* __restrict__ bins, int cap) {
    int role = blockIdx.x & 1;
    int sub  = blockIdx.x >> 1;
    if (role) {                               // ---- bin-scatter role
        int e = sub * 256 + threadIdx.x;
        if (e < EE) {
            int d = edst[e], s = esrc[e];
            if ((unsigned)d < (unsigned)NN && (unsigned)s < (unsigned)NN) {
                int pos = atomicAdd(&counts[d], 1);
                if (pos < cap) bins[d * cap + pos] = (u16)s;  // clamp: no OOB
            }
        }
        return;
    }
    // ---- prep role
    int w = threadIdx.x >> 6, lane = threadIdx.x & 63;
    int gb = (sub * 4 + w) * 8;               // 8 nodes per wave
    __shared__ float xs[4][8][66];
#pragma unroll
    for (int j = 0; j < 8; ++j) {
        int g = gb + j;
        xs[w][j][lane] = state[(size_t)g * UU + lane];
        if (lane == 0) xs[w][j][64] = inputs[g];
    }
    __syncthreads();                          // uniform (all prep threads reach)

    float ak[8], av[8];
#pragma unroll
    for (int j = 0; j < 8; ++j) { ak[j] = 0.f; av[j] = 0.f; }
    for (int f = 0; f < FF; ++f) {            // weight loaded once, 8 nodes reuse
        float wk = Wk[f * UU + lane], wv = Wv[f * UU + lane];
#pragma unroll
        for (int j = 0; j < 8; ++j) {
            float xv = xs[w][j][f];
            ak[j] += xv * wk; av[j] += xv * wv;
        }
    }
    float bkl = bk[lane], bvl = bv[lane];
#pragma unroll
    for (int j = 0; j < 8; ++j) {
        int g = gb + j;
        kbuf[(size_t)g * UU + lane] = f2bf(ak[j] + bkl);
        vbuf[(size_t)g * UU + lane] = f2bf(av[j] + bvl);
        if (lane == 0) maskb[g] = (xs[w][j][58] != 0.0f) ? 1 : 0;
    }
}

// -------------------- fused: 4 nodes/wave, union tiling over bins, GRU
__global__ __launch_bounds__(256) void fused_fast(
    const float* __restrict__ state, const float* __restrict__ inputs,
    const float* __restrict__ Wq, const float* __restrict__ bq,
    const float* __restrict__ Ws, const float* __restrict__ bs,
    const float* __restrict__ W1, const float* __restrict__ b1,
    const float* __restrict__ W2, const float* __restrict__ b2,
    const u16* __restrict__ kbuf, const u16* __restrict__ vbuf,
    const unsigned char* __restrict__ maskb,
    const int* __restrict__ counts, const u16* __restrict__ bins, int cap,
    float* __restrict__ out) {
    int w = threadIdx.x >> 6, lane = threadIdx.x & 63;
    int hl = lane & 31, hf = lane >> 5;

    // XCD-aware swizzle: batch b pinned to XCDs {2b, 2b+1} (r11: FETCH -29%).
    // grid = 5000 = 625*8, dispatch round-robins XCD = bid%8 -> bijective.
    int bid = blockIdx.x;
    int xcd = bid & 7;
    int b   = xcd >> 1;                            // batch 0..3
    int ib  = ((bid >> 3) << 1) | (xcd & 1);       // block-in-batch 0..1249
    int gb  = b * NN + ib * 16 + w * 4;            // 4 consecutive nodes/wave

    __shared__ float xs[4][4][66];            // x rows; later h2 rows
    __shared__ float qs[4][4][68];            // q rows (68: 4-bank row skew)
    __shared__ u64   pl[4][64];               // per-wave {srow,p} publish

#pragma unroll
    for (int j = 0; j < 4; ++j) {
        int g = gb + j;
        xs[w][j][lane] = state[(size_t)g * UU + lane];
        if (lane == 0) xs[w][j][64] = inputs[g];
    }
    __syncthreads();                          // A (uniform)

    // q (pre-scaled) + sproj for 4 nodes; weight value loaded once
    float aq[4], as_[4];
#pragma unroll
    for (int j = 0; j < 4; ++j) { aq[j] = 0.f; as_[j] = 0.f; }
    for (int f = 0; f < FF; ++f) {
        float wq = Wq[f * UU + lane], ws = Ws[f * UU + lane];
#pragma unroll
        for (int j = 0; j < 4; ++j) {
            float xv = xs[w][j][f];
            aq[j] += xv * wq; as_[j] += xv * ws;
        }
    }
    float bql = bq[lane], bsl = bs[lane];
#pragma unroll
    for (int j = 0; j < 4; ++j) {
        as_[j] += bsl;
        qs[w][j][lane] = (aq[j] + bql) * SCALE_F;
    }
    __syncthreads();                          // B (uniform)

    bool mg[4];
#pragma unroll
    for (int j = 0; j < 4; ++j) mg[j] = (xs[w][j][58] != 0.0f);

    const unsigned char* mb = maskb + (size_t)b * NN;
    const u16* kb = kbuf + (size_t)b * NN * UU;
    const u16* vb = vbuf + (size_t)b * NN * UU;
    int nb = gb - b * NN;                     // node base within batch

    // virtual concatenated span over the 4 nodes' bins
    int cum[5]; cum[0] = 0;
    int ebase[4];
#pragma unroll
    for (int j = 0; j < 4; ++j) {
        int dg = counts[nb + j];
        dg = min(max(dg, 0), cap);
        if (!mg[j]) dg = 0;                   // masked dst: skip entire bin
        cum[j + 1] = cum[j] + dg;
        ebase[j] = (nb + j) * cap - cum[j];   // bins addr = ebase[j] + i
    }
    int total = cum[4];

    // accumulators: lane hl holds channels (2hl, 2hl+1) of its half's slots
    float acE[4], acO[4], l[4];
#pragma unroll
    for (int j = 0; j < 4; ++j) { acE[j] = 0.f; acO[j] = 0.f; l[j] = 0.f; }

    const unsigned* vbw = (const unsigned*)vb; // bf16 channel-pair view

    // depth-1 prefetch of tile 0's bin index (named regs only)
    int  s_nxt = 0, jl_nxt = 0;
    bool v_nxt = (lane < total);
    if (v_nxt) {
        jl_nxt = (lane >= cum[1]) + (lane >= cum[2]) + (lane >= cum[3]);
        s_nxt  = bins[ebase[jl_nxt] + lane];
    }

#pragma unroll 1
    for (int tbase = 0; tbase < total; tbase += 64) {
        // rotate prefetched index in; immediately issue next tile's load
        int  s_cur = s_nxt, jl_cur = jl_nxt;
        bool v_cur = v_nxt;
        int inx = tbase + 64 + lane;
        v_nxt = (inx < total);
        if (v_nxt) {
            jl_nxt = (inx >= cum[1]) + (inx >= cum[2]) + (inx >= cum[3]);
            s_nxt  = bins[ebase[jl_nxt] + inx];
        }

        // ---- phase A: lane = edge; mb gather parallel with k gathers
        float p = 0.f; int srow = 0;
        if (v_cur) {
            srow = s_cur;
            unsigned char m = mb[s_cur];      // independent of k loads below
            const uint4* kp = (const uint4*)(kb + ((size_t)s_cur << 6));
            const float* qrow = &qs[w][0][0] + jl_cur * 68;  // per-lane node q
            float d0 = 0.f, d1 = 0.f, d2 = 0.f, d3 = 0.f;
#pragma unroll
            for (int c = 0; c < 8; ++c) {
                uint4 kk = kp[c];
                const float4 qa = *(const float4*)&qrow[c * 8];
                const float4 qc = *(const float4*)&qrow[c * 8 + 4];
                d0 += u2f(kk.x << 16) * qa.x; d1 += u2f(kk.x & 0xFFFF0000u) * qa.y;
                d2 += u2f(kk.y << 16) * qa.z; d3 += u2f(kk.y & 0xFFFF0000u) * qa.w;
                d0 += u2f(kk.z << 16) * qc.x; d1 += u2f(kk.z & 0xFFFF0000u) * qc.y;
                d2 += u2f(kk.w << 16) * qc.z; d3 += u2f(kk.w & 0xFFFF0000u) * qc.w;
            }
            float sc = (d0 + d1) + (d2 + d3);
            p = m ? __expf(sc) : 0.f;         // no-max softmax; mask select
        }
        pl[w][lane] = ((u64)(unsigned)srow << 32) | (u64)__float_as_uint(p);
        __builtin_amdgcn_wave_barrier();

        // ---- phase B: half-wave slot pairing; lane hl = channels 2hl,2hl+1
#pragma unroll
        for (int j = 0; j < 4; ++j) {
            int lo = max(cum[j], tbase);
            int hi = min(cum[j + 1], tbase + 64);
#pragma unroll 1
            for (int s0 = lo; s0 < hi; s0 += 8) {
#pragma unroll
                for (int k2 = 0; k2 < 4; ++k2) {
                    int ss = s0 + 2 * k2 + hf;
                    int sidx = min(ss, hi - 1) - tbase;
                    u64 pk = pl[w][sidx];     // broadcast per half
                    float pj = (ss < hi) ? u2f((unsigned)pk) : 0.f;
                    unsigned sj = (unsigned)(pk >> 32);
                    unsigned v2 = vbw[(sj << 5) | (unsigned)hl];  // 2 channels
                    acE[j] += pj * u2f(v2 << 16);
                    acO[j] += pj * u2f(v2 & 0xFFFF0000u);
                    l[j]   += pj;
                }
            }
        }
        __builtin_amdgcn_wave_barrier();
    }

    // finalize: combine halves, remap channel-pair layout -> lane=channel
#pragma unroll
    for (int j = 0; j < 4; ++j) {
        float lj = l[j]   + __shfl_xor(l[j],   32, 64);
        float aE = acE[j] + __shfl_xor(acE[j], 32, 64);
        float aO = acO[j] + __shfl_xor(acO[j], 32, 64);
        float vE = __shfl(aE, lane >> 1, 64);
        float vO = __shfl(aO, lane >> 1, 64);
        float acc = (lane & 1) ? vO : vE;
        float agg = (lj > 0.f) ? acc / fmaxf(lj, 1e-16f) : 0.f;
        float h2 = mg[j] ? (agg + as_[j]) : xs[w][j][lane];  // masked: pass h
        xs[w][j][lane] = h2;                  // own slot; [64]=xin preserved
    }
    __syncthreads();                          // C (uniform)

    // GRU: value = sigmoid([xin,h2]@W1+b1), c = tanh([xin,r*h2]@W2+b2)
    float xin[4];
#pragma unroll
    for (int j = 0; j < 4; ++j) xin[j] = xs[w][j][64];
    float a1v[4], a2v[4];
#pragma unroll
    for (int j = 0; j < 4; ++j) { a1v[j] = xin[j] * W1[lane]; a2v[j] = xin[j] * W1[UU + lane]; }
    for (int f = 0; f < UU; ++f) {
        float w1a = W1[(f + 1) * 128 + lane], w1b = W1[(f + 1) * 128 + UU + lane];
#pragma unroll
        for (int j = 0; j < 4; ++j) {
            float hv = xs[w][j][f];
            a1v[j] += hv * w1a; a2v[j] += hv * w1b;
        }
    }
    float b1a = b1[lane], b1b = b1[UU + lane];
    float rst[4], z[4];
#pragma unroll
    for (int j = 0; j < 4; ++j) {
        rst[j] = 1.f / (1.f + __expf(-(a1v[j] + b1a)));
        z[j]   = 1.f / (1.f + __expf(-(a2v[j] + b1b)));
        qs[w][j][lane] = rst[j] * xs[w][j][lane];   // reset*h2
    }
    __syncthreads();                          // D (uniform)

    float a3v[4];
#pragma unroll
    for (int j = 0; j < 4; ++j) a3v[j] = xin[j] * W2[lane];
    for (int f = 0; f < UU; ++f) {
        float w2v = W2[(f + 1) * UU + lane];
#pragma unroll
        for (int j = 0; j < 4; ++j) a3v[j] += qs[w][j][f] * w2v;
    }
    float b2l = b2[lane];
#pragma unroll
    for (int j = 0; j < 4; ++j) {
        float a = a3v[j] + b2l;
        float aa = fabsf(a), tt = __expf(-2.f * aa);
        float c = copysignf((1.f - tt) / (1.f + tt), a);
        float h2v_ = xs[w][j][lane];
        out[(size_t)(gb + j) * UU + lane] = (1.f - z[j]) * h2v_ + z[j] * c;
    }
}

// ------------------------------------------------------------------- launch
extern "C" void kernel_launch(void* const* d_in, const int* in_sizes, int n_in,
                              void* d_out, int out_size, void* d_ws, size_t ws_size,
                              hipStream_t stream) {
    const float* inputs = (const float*)d_in[0];
    const float* state  = (const float*)d_in[1];
    if (in_sizes[0] != BB * NN) { inputs = (const float*)d_in[1]; state = (const float*)d_in[0]; }
    const int*   esrc   = (const int*)d_in[2];
    const int*   edst   = (const int*)d_in[3];
    const float* Wq = (const float*)d_in[4];
    const float* bq = (const float*)d_in[5];
    const float* Wk = (const float*)d_in[6];
    const float* bk = (const float*)d_in[7];
    const float* Wv = (const float*)d_in[8];
    const float* bv = (const float*)d_in[9];
    const float* Ws = (const float*)d_in[10];
    const float* bs = (const float*)d_in[11];
    const float* W1 = (const float*)d_in[12];
    const float* b1 = (const float*)d_in[13];
    const float* W2 = (const float*)d_in[14];
    const float* b2 = (const float*)d_in[15];
    float* out = (float*)d_out;

    // workspace carve: fixed parts first, bins take the remainder (cap sized
    // from ws_size; cap=64 needs exactly the r8-proven footprint, cap<=128).
    char* base = (char*)d_ws;
    size_t ofs = 0;
    int* counts = (int*)(base + ofs); ofs = align_up(ofs + (size_t)NN * 4);
    unsigned char* maskb = (unsigned char*)(base + ofs); ofs = align_up(ofs + (size_t)BB * NN);
    u16* kbuf = (u16*)(base + ofs); ofs = align_up(ofs + (size_t)BB * NN * UU * 2);
    u16* vbuf = (u16*)(base + ofs); ofs = align_up(ofs + (size_t)BB * NN * UU * 2);
    u16* bins = (u16*)(base + ofs);
    size_t avail = (ws_size > ofs) ? (ws_size - ofs) : 0;
    int cap = (int)(avail / ((size_t)NN * 2));
    if (cap > 128) cap = 128;
    if (cap < 64)  cap = 64;   // r8-proven budget guarantees this fits
    (void)n_in; (void)out_size;

    hipMemsetAsync(counts, 0, (size_t)NN * 4, stream);
    prep_scatter_kernel<<<PREP_BLOCKS + SCAT_BLOCKS, 256, 0, stream>>>(
        state, inputs, Wk, bk, Wv, bv, kbuf, vbuf, maskb,
        edst, esrc, counts, bins, cap);
    fused_fast<<<(BB * NN) / 16, 256, 0, stream>>>(state, inputs, Wq, bq,
                                                   Ws, bs, W1, b1, W2, b2,
                                                   kbuf, vbuf, maskb,
                                                   counts, bins, cap, out);
}